// Round 2
// baseline (118.646 us; speedup 1.0000x reference)
//
#include <hip/hip_runtime.h>
#include <hip/hip_bf16.h>
#include <stdint.h>

using f32x4  = __attribute__((ext_vector_type(4))) float;
using bf16x8 = __attribute__((ext_vector_type(8))) __bf16;
typedef unsigned int u32;

#define SEQ  4096
#define NEGV -10000.0f

__global__ __launch_bounds__(512) void lattn_kern(
        const float* __restrict__ Q, const float* __restrict__ K,
        const float* __restrict__ V, float* __restrict__ O)
{
    // K: row-major [384][64] bf16, byte ^= (row&7)<<4   (49152 B)
    __shared__ __bf16 Kl[384 * 64];
    // V^T: [64 dims][392 keys] bf16, row stride 784 B    (50176 B)
    __shared__ __bf16 Vt[64 * 392];
    // P: per-wave [16][128] bf16, byte ^= (row&7)<<4    (32768 B)
    __shared__ __bf16 Pl[8][16 * 128];

    const int tid  = threadIdx.x;
    const int wv   = tid >> 6;
    const int lane = tid & 63;
    const int g    = lane >> 4;   // 0..3
    const int c    = lane & 15;   // 0..15

    const int bid = blockIdx.x;
    const int b   = bid >> 5;
    const int nb  = bid & 31;

    const size_t baseB = (size_t)b * (SEQ * 64);

    // ---------------- stage K (row-major swz), V (transposed) ----------------
    // 384 rows x 8 chunks(8 dims) = 3072 chunks; 512 threads x 6
    #pragma unroll
    for (int i = 0; i < 6; ++i) {
        const int ch  = tid + i * 512;
        const int row = ch >> 3;        // 0..383 window key row
        const int dg  = ch & 7;         // 8-dim chunk
        const int seg = row >> 7;       // 0,1,2 -> bins nb-1, nb, nb+1 (circular)
        const int r   = row & 127;
        const int bin = (nb + seg + 31) & 31;
        const size_t ga = baseB + (size_t)(bin * 128 + r) * 64 + dg * 8;

        f32x4 k0 = *(const f32x4*)(K + ga);
        f32x4 k1 = *(const f32x4*)(K + ga + 4);
        f32x4 v0 = *(const f32x4*)(V + ga);
        f32x4 v1 = *(const f32x4*)(V + ga + 4);
        bf16x8 hk;
        #pragma unroll
        for (int u = 0; u < 4; ++u) {
            hk[u] = (__bf16)k0[u]; hk[u + 4] = (__bf16)k1[u];
        }
        u32 kb = ((u32)row << 7) + ((u32)dg << 4);
        kb ^= (u32)(row & 7) << 4;
        *(bf16x8*)((char*)Kl + kb) = hk;

        // V transposed scatter: Vt[dim][key] = V[key][dim]
        #pragma unroll
        for (int u = 0; u < 4; ++u) {
            Vt[(dg * 8 + u)     * 392 + row] = (__bf16)v0[u];
            Vt[(dg * 8 + u + 4) * 392 + row] = (__bf16)v1[u];
        }
    }

    // ---------------- Q fragments (A operand), wave's rows wv*16 + c ----------
    bf16x8 aq[2];
    {
        const float* qp = Q + baseB + (size_t)(nb * 128 + wv * 16 + c) * 64 + g * 8;
        #pragma unroll
        for (int kk = 0; kk < 2; ++kk) {
            f32x4 q0 = *(const f32x4*)(qp + kk * 32);
            f32x4 q1 = *(const f32x4*)(qp + kk * 32 + 4);
            #pragma unroll
            for (int u = 0; u < 4; ++u) {
                aq[kk][u] = (__bf16)q0[u]; aq[kk][u + 4] = (__bf16)q1[u];
            }
        }
    }

    __syncthreads();

    // ---------------- S = (Q K^T): 24 tiles of 16 keys ----------------
    f32x4 s[24];
    #pragma unroll
    for (int t = 0; t < 24; ++t) {
        const u32 key = (u32)(t * 16 + c);
        u32 b0a = (key << 7) + ((u32)g << 4);
        u32 b1a = b0a + 64u;                     // dims 32..63
        const u32 sw = (u32)(c & 7) << 4;
        b0a ^= sw; b1a ^= sw;
        bf16x8 kb0 = *(const bf16x8*)((const char*)Kl + b0a);
        bf16x8 kb1 = *(const bf16x8*)((const char*)Kl + b1a);
        f32x4 acc = {0.f, 0.f, 0.f, 0.f};
        acc = __builtin_amdgcn_mfma_f32_16x16x32_bf16(aq[0], kb0, acc, 0, 0, 0);
        acc = __builtin_amdgcn_mfma_f32_16x16x32_bf16(aq[1], kb1, acc, 0, 0, 0);
        s[t] = acc;
    }

    // ---------------- mask + softmax (row = wv*16 + 4g + r) ----------------
    const int i0 = wv * 16 + g * 4;
    float mx[4] = {-3e38f, -3e38f, -3e38f, -3e38f};
    #pragma unroll
    for (int t = 0; t < 24; ++t) {
        const int j = t * 16 + c;
        #pragma unroll
        for (int r = 0; r < 4; ++r) {
            const int iq = i0 + r - wv * 16;     // row within bin? no: use bin-local
            (void)iq;
        }
    }
    // (bin-local query index for the mask)
    const int iq0 = wv * 16 + g * 4;
    #pragma unroll
    for (int t = 0; t < 24; ++t) {
        const int j = t * 16 + c;
        #pragma unroll
        for (int r = 0; r < 4; ++r) {
            const int iq = iq0 + r;
            float val = s[t][r] * 0.125f;
            const bool m = (j < 128 && j < iq) || (j >= 256 && (j - 256) >= iq);
            val = m ? NEGV : val;
            s[t][r] = val;
            mx[r] = fmaxf(mx[r], val);
        }
    }
    #pragma unroll
    for (int d = 1; d < 16; d <<= 1) {
        #pragma unroll
        for (int r = 0; r < 4; ++r) mx[r] = fmaxf(mx[r], __shfl_xor(mx[r], d, 64));
    }
    float sm[4] = {0.f, 0.f, 0.f, 0.f};
    #pragma unroll
    for (int t = 0; t < 24; ++t) {
        #pragma unroll
        for (int r = 0; r < 4; ++r) {
            float p = __expf(s[t][r] - mx[r]);
            s[t][r] = p; sm[r] += p;
        }
    }
    #pragma unroll
    for (int d = 1; d < 16; d <<= 1) {
        #pragma unroll
        for (int r = 0; r < 4; ++r) sm[r] += __shfl_xor(sm[r], d, 64);
    }
    float inv[4];
    #pragma unroll
    for (int r = 0; r < 4; ++r) inv[r] = 1.0f / sm[r];

    // ---------------- O = P V, per 128-key chunk ----------------
    f32x4 o[4] = {{0,0,0,0},{0,0,0,0},{0,0,0,0},{0,0,0,0}};
    __bf16* Pw = Pl[wv];
    #pragma unroll
    for (int c3 = 0; c3 < 3; ++c3) {
        // write P chunk (D-layout -> row-major swizzled)
        #pragma unroll
        for (int tt = 0; tt < 8; ++tt) {
            const int t = c3 * 8 + tt;
            #pragma unroll
            for (int r = 0; r < 4; ++r) {
                const int prow = g * 4 + r;
                u32 pb = ((u32)prow << 8) + (u32)(tt * 16 + c) * 2u;
                pb ^= (u32)(prow & 7) << 4;
                *(__bf16*)((char*)Pw + pb) = (__bf16)(s[t][r] * inv[r]);
            }
        }
        #pragma unroll
        for (int kk = 0; kk < 4; ++kk) {
            // A-frag: P[row=c][keys kk*32 + 8g .. +8]
            u32 pa_b = ((u32)c << 8) + (u32)(kk * 64 + g * 16);
            pa_b ^= (u32)(c & 7) << 4;
            const bf16x8 pa = *(const bf16x8*)((const char*)Pw + pa_b);

            const int key0 = c3 * 128 + kk * 32 + g * 8;
            #pragma unroll
            for (int dt = 0; dt < 4; ++dt) {
                // B-frag: V[keys key0..+8][dim dt*16+c] = Vt[dt*16+c][key0..+8]
                const bf16x8 bb = *(const bf16x8*)(Vt + (dt * 16 + c) * 392 + key0);
                o[dt] = __builtin_amdgcn_mfma_f32_16x16x32_bf16(pa, bb, o[dt], 0, 0, 0);
            }
        }
    }

    // ---------------- store O (fp32) ----------------
    #pragma unroll
    for (int dt = 0; dt < 4; ++dt) {
        #pragma unroll
        for (int r = 0; r < 4; ++r) {
            const int row = nb * 128 + wv * 16 + g * 4 + r;
            O[baseB + (size_t)row * 64 + dt * 16 + c] = o[dt][r];
        }
    }
}

extern "C" void kernel_launch(void* const* d_in, const int* in_sizes, int n_in,
                              void* d_out, int out_size, void* d_ws, size_t ws_size,
                              hipStream_t stream) {
    const float* q = (const float*)d_in[0];
    const float* k = (const float*)d_in[1];
    const float* v = (const float*)d_in[2];
    float* o = (float*)d_out;
    const int nB = in_sizes[0] / (SEQ * 64);   // 64
    dim3 grid(nB * 32), block(512);
    hipLaunchKernelGGL(lattn_kern, grid, block, 0, stream, q, k, v, o);
}

// Round 3
// 84.916 us; speedup vs baseline: 1.3972x; 1.3972x over previous
//
#include <hip/hip_runtime.h>
#include <hip/hip_bf16.h>
#include <stdint.h>

using f32x4  = __attribute__((ext_vector_type(4))) float;
using bf16x8 = __attribute__((ext_vector_type(8))) __bf16;
using bf16x2 = __attribute__((ext_vector_type(2))) __bf16;
typedef unsigned int u32;

#define SEQ  4096
#define NEGV -10000.0f

__global__ __launch_bounds__(256) void lattn_kern(
        const float* __restrict__ Q, const float* __restrict__ K,
        const float* __restrict__ V, float* __restrict__ O)
{
    // K: row-major [320 keys][64 dims] bf16, 16B-granule ^= (row&7)      (40960 B)
    //    (per-wave 2KB chunks reused as P bounce buffers during PV)
    __shared__ __bf16 Kl[320 * 64];
    // V^T: dim-major [64][320 keys] bf16, 16B-granule ^= (d&7)^((d>>3)&7) (40960 B)
    __shared__ __bf16 Vt[64 * 320];

    const int tid  = threadIdx.x;
    const int wv   = tid >> 6;     // 0..3
    const int lane = tid & 63;
    const int g    = lane >> 4;    // 0..3
    const int c    = lane & 15;    // 0..15

    // XCD-chunked swizzle: HW blocks ≡x (mod 8) get a contiguous logical range
    const int obid = blockIdx.x;
    const int bid  = (obid & 7) * 512 + (obid >> 3);
    const int b    = bid >> 6;     // batch*head
    const int tb   = bid & 63;     // 64-query tile
    const int t0   = tb * 64;

    const size_t baseB = (size_t)b * (SEQ * 64);

    // ---------------- stage K: 320 rows x 8 dim-chunks, 10 iters ----------------
    #pragma unroll
    for (int i = 0; i < 10; ++i) {
        const int ch   = tid + i * 256;
        const int row  = ch >> 3;
        const int dg   = ch & 7;
        const int grow = (t0 - 128 + row) & (SEQ - 1);
        const float* src = K + baseB + (size_t)grow * 64 + dg * 8;
        f32x4 k0 = *(const f32x4*)(src);
        f32x4 k1 = *(const f32x4*)(src + 4);
        bf16x8 hk;
        #pragma unroll
        for (int u = 0; u < 4; ++u) { hk[u] = (__bf16)k0[u]; hk[u + 4] = (__bf16)k1[u]; }
        const u32 kb = (u32)row * 128u + (u32)((dg ^ (row & 7)) * 16);
        *(bf16x8*)((char*)Kl + kb) = hk;
    }

    // ---------------- stage V^T: 160 row-pairs x 8 dim-chunks, 5 iters ----------
    #pragma unroll
    for (int i = 0; i < 5; ++i) {
        const int ch   = tid + i * 256;
        const int rp   = ch >> 3;          // key pair (2rp, 2rp+1)
        const int dg   = ch & 7;
        const int grow = (t0 - 128 + 2 * rp) & (SEQ - 1);   // pair never wraps (even)
        const float* src = V + baseB + (size_t)grow * 64 + dg * 8;
        f32x4 a0 = *(const f32x4*)(src);
        f32x4 a1 = *(const f32x4*)(src + 4);
        f32x4 b0 = *(const f32x4*)(src + 64);
        f32x4 b1 = *(const f32x4*)(src + 68);
        #pragma unroll
        for (int u = 0; u < 8; ++u) {
            const int d  = dg * 8 + u;
            const float lo = (u < 4) ? a0[u] : a1[u - 4];
            const float hi = (u < 4) ? b0[u] : b1[u - 4];
            bf16x2 pv; pv[0] = (__bf16)lo; pv[1] = (__bf16)hi;
            const u32 sw = (u32)(u ^ dg);                  // (d&7)^((d>>3)&7)
            const u32 vb = ((u32)d * 640u + (u32)rp * 4u) ^ (sw << 4);
            *(bf16x2*)((char*)Vt + vb) = pv;
        }
    }

    // ---------------- Q fragments (rows t0 + wv*16 + c) ----------------
    bf16x8 aq[2];
    {
        const float* qp = Q + baseB + (size_t)(t0 + wv * 16 + c) * 64 + g * 8;
        #pragma unroll
        for (int kk = 0; kk < 2; ++kk) {
            f32x4 q0 = *(const f32x4*)(qp + kk * 32);
            f32x4 q1 = *(const f32x4*)(qp + kk * 32 + 4);
            #pragma unroll
            for (int u = 0; u < 4; ++u) { aq[kk][u] = (__bf16)q0[u]; aq[kk][u + 4] = (__bf16)q1[u]; }
        }
    }

    __syncthreads();

    // ---------------- S = Q K^T : live tiles [wv, wv+16] of 20 ----------------
    f32x4 s_[20];
    #pragma unroll
    for (int t = 0; t < 20; ++t) {
        if (t >= wv && t <= wv + 16) {      // wave-uniform
            const u32 key = (u32)(t * 16 + c);
            const u32 sw  = key & 7u;
            const u32 ka  = key * 128u;
            bf16x8 kb0 = *(const bf16x8*)((const char*)Kl + ka + (((u32)g ^ sw) << 4));
            bf16x8 kb1 = *(const bf16x8*)((const char*)Kl + ka + (((u32)(g + 4) ^ sw) << 4));
            f32x4 acc = {0.f, 0.f, 0.f, 0.f};
            __builtin_amdgcn_s_setprio(1);
            acc = __builtin_amdgcn_mfma_f32_16x16x32_bf16(aq[0], kb0, acc, 0, 0, 0);
            acc = __builtin_amdgcn_mfma_f32_16x16x32_bf16(aq[1], kb1, acc, 0, 0, 0);
            __builtin_amdgcn_s_setprio(0);
            s_[t] = acc;
        } else {
            s_[t] = (f32x4){0.f, 0.f, 0.f, 0.f};
        }
    }

    // ---------------- mask + softmax (query i = wv*16 + g*4 + r) ----------------
    const int i0 = wv * 16 + g * 4;
    float mx[4] = {-3e38f, -3e38f, -3e38f, -3e38f};
    #pragma unroll
    for (int t = 0; t < 20; ++t) {
        if (t >= wv && t <= wv + 16) {
            const int j = t * 16 + c;
            #pragma unroll
            for (int r = 0; r < 4; ++r) {
                const int iq = i0 + r;
                float val = s_[t][r] * 0.125f;
                val = (j < iq || j >= iq + 256) ? NEGV : val;
                s_[t][r] = val;
                mx[r] = fmaxf(mx[r], val);
            }
        }
    }
    #pragma unroll
    for (int d = 1; d < 16; d <<= 1) {
        #pragma unroll
        for (int r = 0; r < 4; ++r) mx[r] = fmaxf(mx[r], __shfl_xor(mx[r], d, 64));
    }
    float sm[4] = {0.f, 0.f, 0.f, 0.f};
    #pragma unroll
    for (int t = 0; t < 20; ++t) {
        if (t >= wv && t <= wv + 16) {
            #pragma unroll
            for (int r = 0; r < 4; ++r) {
                float p = __expf(s_[t][r] - mx[r]);
                s_[t][r] = p; sm[r] += p;
            }
        }
    }
    #pragma unroll
    for (int d = 1; d < 16; d <<= 1) {
        #pragma unroll
        for (int r = 0; r < 4; ++r) sm[r] += __shfl_xor(sm[r], d, 64);
    }
    float inv[4];
    #pragma unroll
    for (int r = 0; r < 4; ++r) inv[r] = 1.0f / sm[r];

    __syncthreads();   // all waves done reading Kl as K; safe to alias P into it

    // ---------------- O = P V : 5 chunks of 64 keys ----------------
    f32x4 o[4] = {{0,0,0,0},{0,0,0,0},{0,0,0,0},{0,0,0,0}};
    __bf16* Pw = Kl + wv * 1024;   // per-wave [16 rows][64 keys], granule ^= row&7
    #pragma unroll
    for (int c5 = 0; c5 < 5; ++c5) {
        #pragma unroll
        for (int tt = 0; tt < 4; ++tt) {
            const int t = c5 * 4 + tt;
            #pragma unroll
            for (int r = 0; r < 4; ++r) {
                const int prow = g * 4 + r;
                const u32 pb = ((u32)prow * 128u + (u32)(tt * 16 + c) * 2u)
                             ^ ((u32)(prow & 7) << 4);
                *(__bf16*)((char*)Pw + pb) = (__bf16)(s_[t][r] * inv[r]);
            }
        }
        #pragma unroll
        for (int kk = 0; kk < 2; ++kk) {
            const u32 pa_b = ((u32)c * 128u + (u32)(kk * 64 + g * 16))
                           ^ ((u32)(c & 7) << 4);
            const bf16x8 pa = *(const bf16x8*)((const char*)Pw + pa_b);
            const int key0 = c5 * 64 + kk * 32 + g * 8;
            __builtin_amdgcn_s_setprio(1);
            #pragma unroll
            for (int dt = 0; dt < 4; ++dt) {
                const int d  = dt * 16 + c;
                const u32 sw = (u32)((d & 7) ^ ((d >> 3) & 7));
                const u32 vb = ((u32)d * 640u + (u32)key0 * 2u) ^ (sw << 4);
                const bf16x8 bb = *(const bf16x8*)((const char*)Vt + vb);
                o[dt] = __builtin_amdgcn_mfma_f32_16x16x32_bf16(pa, bb, o[dt], 0, 0, 0);
            }
            __builtin_amdgcn_s_setprio(0);
        }
    }

    // ---------------- store O (fp32) ----------------
    #pragma unroll
    for (int dt = 0; dt < 4; ++dt) {
        #pragma unroll
        for (int r = 0; r < 4; ++r) {
            const int row = t0 + wv * 16 + g * 4 + r;
            O[baseB + (size_t)row * 64 + dt * 16 + c] = o[dt][r];
        }
    }
}

extern "C" void kernel_launch(void* const* d_in, const int* in_sizes, int n_in,
                              void* d_out, int out_size, void* d_ws, size_t ws_size,
                              hipStream_t stream) {
    const float* q = (const float*)d_in[0];
    const float* k = (const float*)d_in[1];
    const float* v = (const float*)d_in[2];
    float* o = (float*)d_out;
    const int nB = in_sizes[0] / (SEQ * 64);   // 64
    dim3 grid(nB * 64), block(256);
    hipLaunchKernelGGL(lattn_kern, grid, block, 0, stream, q, k, v, o);
}

// Round 4
// 83.945 us; speedup vs baseline: 1.4134x; 1.0116x over previous
//
#include <hip/hip_runtime.h>
#include <hip/hip_bf16.h>
#include <stdint.h>

using f32x4  = __attribute__((ext_vector_type(4))) float;
using bf16x8 = __attribute__((ext_vector_type(8))) __bf16;
using bf16x2 = __attribute__((ext_vector_type(2))) __bf16;
typedef unsigned int u32;

#define SEQ 4096

__global__ __launch_bounds__(256, 2) void lattn_kern(
        const float* __restrict__ Q, const float* __restrict__ K,
        const float* __restrict__ V, float* __restrict__ O)
{
    // K ring: [320 rows][64 dims] bf16, 16B-granule ^= (row&7)          (40960 B)
    //   (the 64-row dead slot doubles as the per-wave P bounce buffer)
    __shared__ __bf16 Kl[320 * 64];
    // V^T ring: [64 dims][320 key-cols] bf16, granule ^= (d&7)^((d>>3)&7) (40960 B)
    __shared__ __bf16 Vt[64 * 320];

    const int tid  = threadIdx.x;
    const int wv   = tid >> 6;
    const int lane = tid & 63;
    const int g    = lane >> 4;
    const int c    = lane & 15;

    const int b    = blockIdx.x >> 3;   // head
    const int oct  = blockIdx.x & 7;    // octet of 8 consecutive 64-query tiles
    const size_t baseB = (size_t)b * (SEQ * 64);
    const int t00  = oct * 512;

    int r0 = (t00 + SEQ - 128) % 320;   // ring offset of window start (mult of 64)

    // ---------------- prologue: full 320-key stage for tile 0 ----------------
    #pragma unroll
    for (int it = 0; it < 10; ++it) {
        const int ch = tid + it * 256;
        const int j = ch >> 3, dg = ch & 7;
        const int grow = (t00 - 128 + j) & (SEQ - 1);
        int row = r0 + j; if (row >= 320) row -= 320;
        const float* src = K + baseB + (size_t)grow * 64 + dg * 8;
        f32x4 k0 = *(const f32x4*)src, k1 = *(const f32x4*)(src + 4);
        bf16x8 hk;
        #pragma unroll
        for (int u = 0; u < 4; ++u) { hk[u] = (__bf16)k0[u]; hk[u + 4] = (__bf16)k1[u]; }
        *(bf16x8*)((char*)Kl + row * 128 + (((u32)dg ^ (u32)(row & 7)) << 4)) = hk;
    }
    #pragma unroll
    for (int it = 0; it < 5; ++it) {
        const int ch = tid + it * 256;
        const int rp = ch >> 3, dg = ch & 7;
        const int grow = (t00 - 128 + 2 * rp) & (SEQ - 1);   // even: pair never wraps
        int col = r0 + 2 * rp; if (col >= 320) col -= 320;
        const float* src = V + baseB + (size_t)grow * 64 + dg * 8;
        f32x4 a0 = *(const f32x4*)src,        a1 = *(const f32x4*)(src + 4);
        f32x4 b0 = *(const f32x4*)(src + 64), b1 = *(const f32x4*)(src + 68);
        #pragma unroll
        for (int u = 0; u < 8; ++u) {
            const int d = dg * 8 + u;
            bf16x2 pv;
            pv[0] = (__bf16)((u < 4) ? a0[u] : a1[u - 4]);
            pv[1] = (__bf16)((u < 4) ? b0[u] : b1[u - 4]);
            const u32 sw = (u32)(u ^ dg);
            *(bf16x2*)((char*)Vt + (((u32)d * 640u + (u32)col * 2u) ^ (sw << 4))) = pv;
        }
    }

    const u32 swc = (u32)(c & 7);

    for (int i = 0; i < 8; ++i) {
        const int t0 = t00 + i * 64;
        __syncthreads();                       // B_a: staged window visible

        // ---- early-issue next window's 64 new rows into registers (T14) ----
        f32x4 dk[4], dv[4];
        int krow0 = 0, krow1 = 0, vcol = 0, kdg = 0, vdg = 0;
        if (i < 7) {
            {
                const int jj = tid >> 3; kdg = tid & 7;
                const int grow0 = (t0 + 192 + jj) & (SEQ - 1);
                const float* s0 = K + baseB + (size_t)grow0 * 64 + kdg * 8;
                dk[0] = *(const f32x4*)s0; dk[1] = *(const f32x4*)(s0 + 4);
                krow0 = r0 + jj;
                const int grow1 = (t0 + 192 + jj + 32) & (SEQ - 1);
                const float* s1 = K + baseB + (size_t)grow1 * 64 + kdg * 8;
                dk[2] = *(const f32x4*)s1; dk[3] = *(const f32x4*)(s1 + 4);
                krow1 = r0 + jj + 32;
            }
            {
                const int rp = tid >> 3; vdg = tid & 7;
                const int grow = (t0 + 192 + 2 * rp) & (SEQ - 1);
                const float* s0 = V + baseB + (size_t)grow * 64 + vdg * 8;
                dv[0] = *(const f32x4*)s0;        dv[1] = *(const f32x4*)(s0 + 4);
                dv[2] = *(const f32x4*)(s0 + 64); dv[3] = *(const f32x4*)(s0 + 68);
                vcol = r0 + 2 * rp;
            }
        }

        // ---- Q fragments ----
        bf16x8 aq0, aq1;
        {
            const float* qp = Q + baseB + (size_t)(t0 + wv * 16 + c) * 64 + g * 8;
            f32x4 q0 = *(const f32x4*)qp,        q1 = *(const f32x4*)(qp + 4);
            f32x4 q2 = *(const f32x4*)(qp + 32), q3 = *(const f32x4*)(qp + 36);
            #pragma unroll
            for (int u = 0; u < 4; ++u) {
                aq0[u] = (__bf16)q0[u]; aq0[u + 4] = (__bf16)q1[u];
                aq1[u] = (__bf16)q2[u]; aq1[u + 4] = (__bf16)q3[u];
            }
        }

        // ---- S = Q K^T (live tiles t in [wv, wv+16]) ----
        f32x4 s_[20];
        const int rc = r0 + c;
        #pragma unroll
        for (int t = 0; t < 20; ++t) {
            if (t >= wv && t <= wv + 16) {
                int row = rc + 16 * t; if (row >= 320) row -= 320;
                const u32 ka = (u32)row * 128u;
                bf16x8 kb0 = *(const bf16x8*)((const char*)Kl + ka + (((u32)g ^ swc) << 4));
                bf16x8 kb1 = *(const bf16x8*)((const char*)Kl + ka + (((u32)(g + 4) ^ swc) << 4));
                f32x4 acc = {0.f, 0.f, 0.f, 0.f};
                __builtin_amdgcn_s_setprio(1);
                acc = __builtin_amdgcn_mfma_f32_16x16x32_bf16(aq0, kb0, acc, 0, 0, 0);
                acc = __builtin_amdgcn_mfma_f32_16x16x32_bf16(aq1, kb1, acc, 0, 0, 0);
                __builtin_amdgcn_s_setprio(0);
                s_[t] = acc;
            } else {
                s_[t] = (f32x4){0.f, 0.f, 0.f, 0.f};
            }
        }
        __syncthreads();                       // B_b: QK reads done; dead slot free

        // ---- softmax (no max-subtract; mask only on first/last live tile) ----
        float sm4[4] = {0.f, 0.f, 0.f, 0.f};
        #pragma unroll
        for (int t = 0; t < 20; ++t) {
            if (t >= wv && t <= wv + 16) {
                #pragma unroll
                for (int r = 0; r < 4; ++r) {
                    float e = __expf(s_[t][r] * 0.125f);
                    if (t == wv)      e = (c <  g * 4 + r) ? 0.f : e;
                    if (t == wv + 16) e = (c >= g * 4 + r) ? 0.f : e;
                    s_[t][r] = e; sm4[r] += e;
                }
            }
        }
        #pragma unroll
        for (int d = 1; d < 16; d <<= 1) {
            #pragma unroll
            for (int r = 0; r < 4; ++r) sm4[r] += __shfl_xor(sm4[r], d, 64);
        }
        float inv[4];
        #pragma unroll
        for (int r = 0; r < 4; ++r) inv[r] = 1.0f / sm4[r];

        // ---- O = P V (P bounced through the dead K slot, unnormalized) ----
        char* Pw = (char*)Kl + r0 * 128 + wv * 2048;
        f32x4 o[4] = {{0,0,0,0},{0,0,0,0},{0,0,0,0},{0,0,0,0}};
        #pragma unroll
        for (int c5 = 0; c5 < 5; ++c5) {
            #pragma unroll
            for (int tt = 0; tt < 4; ++tt) {
                const int t = c5 * 4 + tt;
                const bool live = (t >= wv && t <= wv + 16);
                #pragma unroll
                for (int r = 0; r < 4; ++r) {
                    const int prow = g * 4 + r;
                    const u32 pb = ((u32)prow * 128u + (u32)(tt * 16 + c) * 2u)
                                 ^ ((u32)(prow & 7) << 4);
                    float pv_ = live ? s_[t][r] : 0.f;
                    *(__bf16*)(Pw + pb) = (__bf16)pv_;
                }
            }
            #pragma unroll
            for (int kk = 0; kk < 2; ++kk) {
                const u32 pa_b = ((u32)c * 128u + (u32)(kk * 64 + g * 16)) ^ (swc << 4);
                const bf16x8 pa = *(const bf16x8*)(Pw + pa_b);
                int col0 = r0 + c5 * 64 + kk * 32 + g * 8;
                if (col0 >= 320) col0 -= 320;
                __builtin_amdgcn_s_setprio(1);
                #pragma unroll
                for (int dt = 0; dt < 4; ++dt) {
                    const int d  = dt * 16 + c;
                    const u32 sw = (u32)((d & 7) ^ ((d >> 3) & 7));
                    const u32 vb = ((u32)d * 640u + (u32)col0 * 2u) ^ (sw << 4);
                    const bf16x8 bb = *(const bf16x8*)((const char*)Vt + vb);
                    o[dt] = __builtin_amdgcn_mfma_f32_16x16x32_bf16(pa, bb, o[dt], 0, 0, 0);
                }
                __builtin_amdgcn_s_setprio(0);
            }
        }

        // ---- store O (scaled by 1/sum) ----
        #pragma unroll
        for (int dt = 0; dt < 4; ++dt) {
            #pragma unroll
            for (int r = 0; r < 4; ++r) {
                const int row = t0 + wv * 16 + g * 4 + r;
                O[baseB + (size_t)row * 64 + dt * 16 + c] = o[dt][r] * inv[r];
            }
        }

        // ---- write delta into ring (dead slot) for next tile ----
        if (i < 7) {
            __syncthreads();                   // B_c: P reads + V evict reads done
            bf16x8 hk;
            #pragma unroll
            for (int u = 0; u < 4; ++u) { hk[u] = (__bf16)dk[0][u]; hk[u + 4] = (__bf16)dk[1][u]; }
            *(bf16x8*)((char*)Kl + krow0 * 128 + (((u32)kdg ^ (u32)(krow0 & 7)) << 4)) = hk;
            #pragma unroll
            for (int u = 0; u < 4; ++u) { hk[u] = (__bf16)dk[2][u]; hk[u + 4] = (__bf16)dk[3][u]; }
            *(bf16x8*)((char*)Kl + krow1 * 128 + (((u32)kdg ^ (u32)(krow1 & 7)) << 4)) = hk;
            #pragma unroll
            for (int u = 0; u < 8; ++u) {
                const int d = vdg * 8 + u;
                bf16x2 pv;
                pv[0] = (__bf16)((u < 4) ? dv[0][u] : dv[1][u - 4]);
                pv[1] = (__bf16)((u < 4) ? dv[2][u] : dv[3][u - 4]);
                const u32 sw = (u32)(u ^ vdg);
                *(bf16x2*)((char*)Vt + (((u32)d * 640u + (u32)vcol * 2u) ^ (sw << 4))) = pv;
            }
            r0 += 64; if (r0 >= 320) r0 -= 320;
        }
    }
}

extern "C" void kernel_launch(void* const* d_in, const int* in_sizes, int n_in,
                              void* d_out, int out_size, void* d_ws, size_t ws_size,
                              hipStream_t stream) {
    const float* q = (const float*)d_in[0];
    const float* k = (const float*)d_in[1];
    const float* v = (const float*)d_in[2];
    float* o = (float*)d_out;
    const int nB = in_sizes[0] / (SEQ * 64);   // 64
    dim3 grid(nB * 8), block(256);
    hipLaunchKernelGGL(lattn_kern, grid, block, 0, stream, q, k, v, o);
}

// Round 5
// 71.691 us; speedup vs baseline: 1.6550x; 1.1709x over previous
//
#include <hip/hip_runtime.h>
#include <hip/hip_bf16.h>
#include <stdint.h>

using f32x4  = __attribute__((ext_vector_type(4))) float;
using bf16x8 = __attribute__((ext_vector_type(8))) __bf16;
using bf16x4 = __attribute__((ext_vector_type(4))) __bf16;
using bf16x2 = __attribute__((ext_vector_type(2))) __bf16;
typedef unsigned int u32;

#define SEQ 4096

// D[q 4g+r][d c] += A[q c][k 4g+e] * B[k 4g+e][d c]   (K=16 keys)
__device__ __forceinline__ void mfma16(f32x4& acc, bf16x4 a, bf16x4 b) {
    asm volatile("v_mfma_f32_16x16x16_bf16 %0, %1, %2, %0"
                 : "+v"(acc) : "v"(a), "v"(b));
}

__global__ __launch_bounds__(256, 2) void lattn_kern(
        const float* __restrict__ Q, const float* __restrict__ K,
        const float* __restrict__ V, float* __restrict__ O)
{
    // K ring: [320 rows][64 dims] bf16, 16B-granule ^= (row&7)            (40960 B)
    __shared__ __bf16 Kl[320 * 64];
    // V^T ring: [64 dims][320 key-cols] bf16, granule ^= (d&7)^((d>>3)&7) (40960 B)
    __shared__ __bf16 Vt[64 * 320];

    const int tid  = threadIdx.x;
    const int wv   = tid >> 6;
    const int lane = tid & 63;
    const int g    = lane >> 4;
    const int c    = lane & 15;
    const u32 swc  = (u32)(c & 7);

    const int b    = blockIdx.x >> 3;
    const int oct  = blockIdx.x & 7;
    const size_t baseB = (size_t)b * (SEQ * 64);
    const int t00  = oct * 512;

    int r0 = (t00 + SEQ - 128) % 320;

    // ---------------- prologue: stage full 320-key window ----------------
    #pragma unroll
    for (int it = 0; it < 10; ++it) {
        const int ch = tid + it * 256;
        const int j = ch >> 3, dg = ch & 7;
        const int grow = (t00 - 128 + j) & (SEQ - 1);
        int row = r0 + j; if (row >= 320) row -= 320;
        const float* src = K + baseB + (size_t)grow * 64 + dg * 8;
        f32x4 k0 = *(const f32x4*)src, k1 = *(const f32x4*)(src + 4);
        bf16x8 hk;
        #pragma unroll
        for (int u = 0; u < 4; ++u) { hk[u] = (__bf16)k0[u]; hk[u + 4] = (__bf16)k1[u]; }
        *(bf16x8*)((char*)Kl + row * 128 + (((u32)dg ^ (u32)(row & 7)) << 4)) = hk;
    }
    #pragma unroll
    for (int it = 0; it < 5; ++it) {
        const int ch = tid + it * 256;
        const int rp = ch >> 3, dg = ch & 7;
        const int grow = (t00 - 128 + 2 * rp) & (SEQ - 1);
        int col = r0 + 2 * rp; if (col >= 320) col -= 320;
        const float* src = V + baseB + (size_t)grow * 64 + dg * 8;
        f32x4 a0 = *(const f32x4*)src,        a1 = *(const f32x4*)(src + 4);
        f32x4 b0 = *(const f32x4*)(src + 64), b1 = *(const f32x4*)(src + 68);
        #pragma unroll
        for (int u = 0; u < 8; ++u) {
            const int d = dg * 8 + u;
            bf16x2 pv;
            pv[0] = (__bf16)((u < 4) ? a0[u] : a1[u - 4]);
            pv[1] = (__bf16)((u < 4) ? b0[u] : b1[u - 4]);
            const u32 sw = (u32)(u ^ dg);
            *(bf16x2*)((char*)Vt + (((u32)d * 640u + (u32)col * 2u) ^ (sw << 4))) = pv;
        }
    }

    // ---------------- prologue: Q frags for tile 0 ----------------
    bf16x8 aq0, aq1;
    {
        const float* qp = Q + baseB + (size_t)(t00 + wv * 16 + c) * 64 + g * 8;
        f32x4 q0 = *(const f32x4*)qp,        q1 = *(const f32x4*)(qp + 4);
        f32x4 q2 = *(const f32x4*)(qp + 32), q3 = *(const f32x4*)(qp + 36);
        #pragma unroll
        for (int u = 0; u < 4; ++u) {
            aq0[u] = (__bf16)q0[u]; aq0[u + 4] = (__bf16)q1[u];
            aq1[u] = (__bf16)q2[u]; aq1[u + 4] = (__bf16)q3[u];
        }
    }

    for (int i = 0; i < 8; ++i) {
        const int t0 = t00 + i * 64;
        __syncthreads();                       // B_a: staged window visible

        // ---- S^T = K Q^T : 17 live tiles, lane holds [key 4g+r][query c] ----
        f32x4 s_[17];
        const int rb = r0 + 16 * wv + c;
        __builtin_amdgcn_s_setprio(1);
        #pragma unroll
        for (int lt = 0; lt < 17; ++lt) {
            int row = rb + 16 * lt; if (row >= 320) row -= 320;
            const char* ka = (const char*)Kl + (u32)row * 128u;
            bf16x8 a0 = *(const bf16x8*)(ka + (((u32)g ^ swc) << 4));
            bf16x8 a1 = *(const bf16x8*)(ka + (((u32)(g + 4) ^ swc) << 4));
            f32x4 acc = {0.f, 0.f, 0.f, 0.f};
            acc = __builtin_amdgcn_mfma_f32_16x16x32_bf16(a0, aq0, acc, 0, 0, 0);
            acc = __builtin_amdgcn_mfma_f32_16x16x32_bf16(a1, aq1, acc, 0, 0, 0);
            s_[lt] = acc;
        }
        __builtin_amdgcn_s_setprio(0);

        // ---- early-issue next tile's Q + K/V delta (hidden under softmax+PV) ----
        f32x4 qn0, qn1, qn2, qn3, dk[4], dv[4];
        int krow0 = 0, krow1 = 0, vcol = 0, kdg = 0, vdg = 0;
        if (i < 7) {
            const float* qp = Q + baseB + (size_t)(t0 + 64 + wv * 16 + c) * 64 + g * 8;
            qn0 = *(const f32x4*)qp;        qn1 = *(const f32x4*)(qp + 4);
            qn2 = *(const f32x4*)(qp + 32); qn3 = *(const f32x4*)(qp + 36);
            {
                const int jj = tid >> 3; kdg = tid & 7;
                const int grow0 = (t0 + 192 + jj) & (SEQ - 1);
                const float* s0 = K + baseB + (size_t)grow0 * 64 + kdg * 8;
                dk[0] = *(const f32x4*)s0; dk[1] = *(const f32x4*)(s0 + 4);
                krow0 = r0 + jj;
                const int grow1 = (t0 + 192 + jj + 32) & (SEQ - 1);
                const float* s1 = K + baseB + (size_t)grow1 * 64 + kdg * 8;
                dk[2] = *(const f32x4*)s1; dk[3] = *(const f32x4*)(s1 + 4);
                krow1 = r0 + jj + 32;
            }
            {
                const int rp = tid >> 3; vdg = tid & 7;
                const int grow = (t0 + 192 + 2 * rp) & (SEQ - 1);
                const float* s0 = V + baseB + (size_t)grow * 64 + vdg * 8;
                dv[0] = *(const f32x4*)s0;        dv[1] = *(const f32x4*)(s0 + 4);
                dv[2] = *(const f32x4*)(s0 + 64); dv[3] = *(const f32x4*)(s0 + 68);
                vcol = r0 + 2 * rp;
            }
        }

        // ---- softmax over keys of query c (no max-subtract; edge masks only) ----
        const int k4 = 4 * g;
        float sum = 0.f;
        #pragma unroll
        for (int lt = 0; lt < 17; ++lt) {
            #pragma unroll
            for (int r = 0; r < 4; ++r) {
                float e = exp2f(s_[lt][r] * 0.18033688f);   // 0.125*log2(e)
                if (lt == 0)  e = (k4 + r <  c) ? 0.f : e;
                if (lt == 16) e = (k4 + r >= c) ? 0.f : e;
                s_[lt][r] = e; sum += e;
            }
        }
        sum += __shfl_xor(sum, 16, 64);
        sum += __shfl_xor(sum, 32, 64);
        const float inv = 1.0f / sum;

        // ---- P -> bf16 A-frags, in-register (no LDS bounce) ----
        bf16x4 pa[17];
        #pragma unroll
        for (int lt = 0; lt < 17; ++lt) {
            #pragma unroll
            for (int r = 0; r < 4; ++r) pa[lt][r] = (__bf16)(s_[lt][r] * inv);
        }

        // ---- O = P V : per tile, 4 dim-tiles, K=16 keys ----
        f32x4 o[4] = {{0,0,0,0},{0,0,0,0},{0,0,0,0},{0,0,0,0}};
        const int cb = r0 + 16 * wv + 4 * g;
        __builtin_amdgcn_s_setprio(1);
        #pragma unroll
        for (int lt = 0; lt < 17; ++lt) {
            int col = cb + 16 * lt; if (col >= 320) col -= 320;
            #pragma unroll
            for (int dt = 0; dt < 4; ++dt) {
                const int d  = dt * 16 + c;
                const u32 sw = (u32)((d & 7) ^ ((d >> 3) & 7));
                const u32 vb = ((u32)d * 640u + (u32)col * 2u) ^ (sw << 4);
                const bf16x4 vbf = *(const bf16x4*)((const char*)Vt + vb);
                mfma16(o[dt], pa[lt], vbf);
            }
        }
        __builtin_amdgcn_s_setprio(0);
        asm volatile("s_nop 7\n\ts_nop 7" ::);   // MFMA->VMEM read hazard guard

        // ---- store O: lane (g,c) holds queries 4g+r, dims dt*16+c ----
        #pragma unroll
        for (int dt = 0; dt < 4; ++dt) {
            #pragma unroll
            for (int r = 0; r < 4; ++r) {
                const int row = t0 + wv * 16 + 4 * g + r;
                O[baseB + (size_t)row * 64 + dt * 16 + c] = o[dt][r];
            }
        }

        // ---- ring update: write delta into dead slot, roll Q frags ----
        if (i < 7) {
            __syncthreads();                   // B_c: all reads of old rows done
            bf16x8 hk;
            #pragma unroll
            for (int u = 0; u < 4; ++u) { hk[u] = (__bf16)dk[0][u]; hk[u + 4] = (__bf16)dk[1][u]; }
            *(bf16x8*)((char*)Kl + krow0 * 128 + (((u32)kdg ^ (u32)(krow0 & 7)) << 4)) = hk;
            #pragma unroll
            for (int u = 0; u < 4; ++u) { hk[u] = (__bf16)dk[2][u]; hk[u + 4] = (__bf16)dk[3][u]; }
            *(bf16x8*)((char*)Kl + krow1 * 128 + (((u32)kdg ^ (u32)(krow1 & 7)) << 4)) = hk;
            #pragma unroll
            for (int u = 0; u < 8; ++u) {
                const int d = vdg * 8 + u;
                bf16x2 pv;
                pv[0] = (__bf16)((u < 4) ? dv[0][u] : dv[1][u - 4]);
                pv[1] = (__bf16)((u < 4) ? dv[2][u] : dv[3][u - 4]);
                const u32 sw = (u32)(u ^ vdg);
                *(bf16x2*)((char*)Vt + (((u32)d * 640u + (u32)vcol * 2u) ^ (sw << 4))) = pv;
            }
            r0 += 64; if (r0 >= 320) r0 -= 320;
            #pragma unroll
            for (int u = 0; u < 4; ++u) {
                aq0[u] = (__bf16)qn0[u]; aq0[u + 4] = (__bf16)qn1[u];
                aq1[u] = (__bf16)qn2[u]; aq1[u + 4] = (__bf16)qn3[u];
            }
        }
    }
}

extern "C" void kernel_launch(void* const* d_in, const int* in_sizes, int n_in,
                              void* d_out, int out_size, void* d_ws, size_t ws_size,
                              hipStream_t stream) {
    const float* q = (const float*)d_in[0];
    const float* k = (const float*)d_in[1];
    const float* v = (const float*)d_in[2];
    float* o = (float*)d_out;
    const int nB = in_sizes[0] / (SEQ * 64);   // 64
    dim3 grid(nB * 8), block(256);
    hipLaunchKernelGGL(lattn_kern, grid, block, 0, stream, q, k, v, o);
}